// Round 11
// baseline (385.109 us; speedup 1.0000x reference)
//
#include <hip/hip_runtime.h>

#define B_ 512
#define T_ 256
#define F_ 8
#define H_ 128
#define BT_ (B_*T_)
#define MH_ 512
#define L2E 1.4426950408889634f

typedef __attribute__((ext_vector_type(4))) float f32x4;
typedef __attribute__((ext_vector_type(8))) __bf16 bf16x8;

// Static device scratch
// g_w2t: W2^T bf16, row n holds k-elems PRE-SWIZZLED: elem (k ^ ((n&7)<<3)).
__device__ unsigned short g_w2t[MH_*MH_];
// packed Whh/Wih bf16, [head][pc][k], PRE-SCALED: i,f,o rows by -log2e, g rows by +2log2e
__device__ unsigned short g_whh[3][512][128];
__device__ unsigned short g_wih[3][512][32];
__device__ unsigned short g_xbf[3][B_*T_*F_];        // x in bf16, same (B,T,F) layout
__device__ unsigned short g_hwd[3][16][128];         // head-dot B panel: col0=hw, cols1-15=0

__device__ __forceinline__ unsigned short f2bf(float f){
  unsigned int u = __float_as_uint(f);
  unsigned int r = (u + 0x7FFFu + ((u >> 16) & 1u)) >> 16;  // RNE
  return (unsigned short)r;
}
__device__ __forceinline__ unsigned short cvt_bf16(float f){
  union { __bf16 b; unsigned short u; } c;
  c.b = (__bf16)f;                                   // single v_cvt, RNE
  return c.u;
}

#if __has_builtin(__builtin_amdgcn_exp2f)
#define EXP2F __builtin_amdgcn_exp2f
#else
#define EXP2F exp2f
#endif
#define RCPF __builtin_amdgcn_rcpf

struct LstmArgs {
  const float* x[3];
  const float* Wih[3];
  const float* Whh[3];
  const float* bias[3];
  const float* hw[3];
  const float* hb[3];
  float* out;
};

// Pack Whh/Wih into MFMA column order (pre-scaled by +-log2e), x to bf16,
// and the head-dot panel g_hwd (col 0 = hw, other cols 0).
__global__ __launch_bounds__(256) void prep_lstm(LstmArgs A){
  const int NW = 3*512*128;
  const int NI = 3*512*32;
  const int NX = 3*B_*T_*F_;
  const int NH = 3*16*128;
  for (int i = blockIdx.x*256 + threadIdx.x; i < NW+NI+NX+NH; i += gridDim.x*256){
    if (i < NW){
      int head = i >> 16;
      int r = i & 65535;
      int pc = r >> 7, k = r & 127;
      int w = pc >> 6, g = (pc >> 4) & 3, s = pc & 15;
      int row = g*128 + w*16 + s;
      float sc = (g == 2) ? (2.0f*L2E) : (-L2E);
      g_whh[head][pc][k] = f2bf(A.Whh[head][row*H_ + k] * sc);
    } else if (i < NW + NI){
      int j = i - NW;
      int head = j >> 14;
      int r = j & 16383;
      int pc = r >> 5, k = r & 31;
      int w = pc >> 6, g = (pc >> 4) & 3, s = pc & 15;
      int row = g*128 + w*16 + s;
      float sc = (g == 2) ? (2.0f*L2E) : (-L2E);
      g_wih[head][pc][k] = (k < 8) ? f2bf(A.Wih[head][row*F_ + k] * sc) : (unsigned short)0;
    } else if (i < NW + NI + NX){
      int j = i - NW - NI;
      int head = j >> 20;
      int r = j & 1048575;
      g_xbf[head][r] = f2bf(A.x[head][r]);
    } else {
      int j = i - NW - NI - NX;
      int head = j >> 11;                  // /2048
      int r = j & 2047;
      int col = r >> 7, k = r & 127;
      g_hwd[head][col][k] = (col == 0) ? f2bf(A.hw[head][k]) : (unsigned short)0;
    }
  }
}

// MFMA LSTM, 8-batch row-spread tiles, 192 blocks, issue-optimized:
//  - bias pre-loaded into MFMA C-operand (acc init = bias splat)
//  - head-dot D = h.hw as 4 extra MFMAs on wave 0 only (B panel g_hwd),
//    one step late (uses ah = h_{ts-1}); direct global store, no shfl/part
//  - LDS addresses hoisted; buffer toggle = one uniform XOR
//  - native __bf16 converts (1 v_cvt each)
__global__ __launch_bounds__(512) void lstm_mfma_kernel(LstmArgs A){
  const int head   = blockIdx.x >> 6;          // 64 tiles per head, 192 blocks
  const int batch0 = (blockIdx.x & 63) * 8;
  const int tid = threadIdx.x;
  const int w   = tid >> 6;
  const int l   = tid & 63;
  const int c16 = l & 15;
  const int kb  = (l >> 4) * 8;

  const float* __restrict__ bs  = A.bias[head];
  const float hbv = A.hb[head][0];
  float* __restrict__ D = A.out + (size_t)head * BT_;

  // register-resident B-fragments
  bf16x8 bh[4][4];
  bf16x8 bx[4];
  #pragma unroll
  for (int g = 0; g < 4; ++g){
    const int pc = w*64 + g*16 + c16;
    #pragma unroll
    for (int kk = 0; kk < 4; ++kk)
      bh[g][kk] = *(const bf16x8*)&g_whh[head][pc][kk*32 + kb];
    bx[g] = *(const bf16x8*)&g_wih[head][pc][kb];
  }
  // head-dot panel fragments (only wave 0 consumes them)
  bf16x8 bD[4];
  if (w == 0){
    #pragma unroll
    for (int kk = 0; kk < 4; ++kk)
      bD[kk] = *(const bf16x8*)&g_hwd[head][c16][kk*32 + kb];
  }

  const int u = w*16 + c16;
  const float bi_ = bs[u]        * (-L2E);
  const float bf_ = bs[H_+u]     * (-L2E);
  const float bg_ = bs[2*H_+u]   * (2.0f*L2E);
  const float bo_ = bs[3*H_+u]   * (-L2E);

  __shared__ __align__(16) unsigned short h_bf[2][16][132];

  for (int i = tid; i < 2*16*132; i += 512) ((unsigned short*)h_bf)[i] = 0;

  float cst[2] = {0.f, 0.f};

  // hoisted LDS element offsets (buffer stride = 16*132 = 2112 elems)
  unsigned short* const hb0 = &h_bf[0][0][0];
  const int rdbase = c16*132 + kb;
  const int wrbase = ((l >> 4)*4)*132 + u;
  int curo = 0;

  // x A-row mapping: lane c16 supplies A-row c16; valid rows {0,1,4,5,8,9,12,13}
  const int bt = ((c16 >> 2) << 1) | (c16 & 1);
  const bool xvalid = (l < 16) && !(l & 2);
  const unsigned short* __restrict__ xrow =
      &g_xbf[head][(size_t)(batch0 + bt) * (T_*F_)];

  // D store pointers for wave 0, lanes c16==0 (l = 0,16,32,48)
  float* __restrict__ Dp = D + (size_t)(batch0 + 2*(l >> 4)) * T_;

  bf16x8 ax_cur = {};
  if (xvalid) ax_cur = *(const bf16x8*)(xrow);

  __syncthreads();

  for (int ts = 0; ts < T_; ++ts){
    // A-frags for current h (= h_{ts-1})
    bf16x8 ah[4];
    #pragma unroll
    for (int kk = 0; kk < 4; ++kk)
      ah[kk] = *(const bf16x8*)(hb0 + curo + rdbase + kk*32);

    // prefetch next step's x (off the critical path)
    bf16x8 ax_nxt = {};
    {
      const int tn = (ts + 1 < T_) ? ts + 1 : ts;
      if (xvalid) ax_nxt = *(const bf16x8*)(xrow + tn*F_);
    }

    // gate MFMAs: acc starts at bias splat; h-MFMAs then x-MFMA
    f32x4 acc[4];
    acc[0] = (f32x4){bi_, bi_, bi_, bi_};
    acc[1] = (f32x4){bf_, bf_, bf_, bf_};
    acc[2] = (f32x4){bg_, bg_, bg_, bg_};
    acc[3] = (f32x4){bo_, bo_, bo_, bo_};
    #pragma unroll
    for (int kk = 0; kk < 4; ++kk){
      #pragma unroll
      for (int g = 0; g < 4; ++g)
        acc[g] = __builtin_amdgcn_mfma_f32_16x16x32_bf16(ah[kk], bh[g][kk], acc[g], 0, 0, 0);
    }
    #pragma unroll
    for (int g = 0; g < 4; ++g)
      acc[g] = __builtin_amdgcn_mfma_f32_16x16x32_bf16(ax_cur, bx[g], acc[g], 0, 0, 0);

    // head-dot D_{ts-1} = h_{ts-1}.hw + hb via MFMA (wave 0 only)
    if (w == 0){
      f32x4 accD = {hbv, hbv, hbv, hbv};
      #pragma unroll
      for (int kk = 0; kk < 4; ++kk)
        accD = __builtin_amdgcn_mfma_f32_16x16x32_bf16(ah[kk], bD[kk], accD, 0, 0, 0);
      if (ts > 0 && c16 == 0){
        Dp[ts-1]      = accD[0];
        Dp[T_ + ts-1] = accD[1];
      }
    }

    // cell update: 2 cells/lane (regs r=0,1), exp2-form gates (bias already in)
    unsigned short* const hw_ptr = hb0 + (curo ^ 2112) + wrbase;
    #pragma unroll
    for (int r = 0; r < 2; ++r){
      const float si = RCPF(1.f + EXP2F(acc[0][r]));
      const float sf = RCPF(1.f + EXP2F(acc[1][r]));
      const float tg = 1.f - 2.f * RCPF(EXP2F(acc[2][r]) + 1.f);
      const float so = RCPF(1.f + EXP2F(acc[3][r]));
      cst[r] = sf * cst[r] + si * tg;
      const float tc = 1.f - 2.f * RCPF(EXP2F(cst[r] * (2.0f*L2E)) + 1.f);
      hw_ptr[r*132] = cvt_bf16(so * tc);
    }

    __syncthreads();                            // new h visible
    curo ^= 2112;
    ax_cur = ax_nxt;
  }

  // epilogue: D_{T-1} from the final h buffer
  if (w == 0){
    bf16x8 ah[4];
    #pragma unroll
    for (int kk = 0; kk < 4; ++kk)
      ah[kk] = *(const bf16x8*)(hb0 + curo + rdbase + kk*32);
    f32x4 accD = {hbv, hbv, hbv, hbv};
    #pragma unroll
    for (int kk = 0; kk < 4; ++kk)
      accD = __builtin_amdgcn_mfma_f32_16x16x32_bf16(ah[kk], bD[kk], accD, 0, 0, 0);
    if (c16 == 0){
      Dp[T_-1]      = accD[0];
      Dp[T_ + T_-1] = accD[1];
    }
  }
}

// W2 (k-major, f32) -> g_w2t (n-major, bf16), pre-swizzled within each row.
__global__ __launch_bounds__(256) void prep_w2t(const float* __restrict__ W2){
  const int idx = blockIdx.x * 256 + threadIdx.x;   // = n*512 + k
  const int n = idx >> 9;
  const int k = idx & 511;
  g_w2t[(n << 9) | (k ^ ((n & 7) << 3))] = f2bf(W2[(size_t)k * MH_ + n]);
}

// Fused MLP v3 (round-10, verified ~50us): 256 threads, 128 rows/block,
// grid 1024, launch_bounds(256,2). afr computed once (128 VGPR, fits in 256
// cap). Full N in 16 passes of 32 cols; W2 slice double-buffered in LDS.
__global__ __launch_bounds__(256, 2) void mlp_kernel(
    const float* __restrict__ Dbase,
    const float* __restrict__ W1, const float* __restrict__ b1,
    const float* __restrict__ b2, const float* __restrict__ W3,
    const float* __restrict__ b3, float* __restrict__ out)
{
  __shared__ __align__(16) unsigned short buf[2][32*512];   // 2 x 32KB

  const int tid = threadIdx.x;
  const int l   = tid & 63;
  const int c16 = l & 15;
  const int kb  = (l >> 4) * 8;
  const int w   = tid >> 6;                 // 0..3
  const int m0  = blockIdx.x * 128 + w * 32;

  // A fragments for 2 M-tiles (computed once; live for whole kernel)
  bf16x8 afr[2][16];
  {
    float d[2][3];
    #pragma unroll
    for (int mt = 0; mt < 2; ++mt){
      const int gr = m0 + mt*16 + c16;
      d[mt][0] = Dbase[gr];
      d[mt][1] = Dbase[BT_ + gr];
      d[mt][2] = Dbase[2*BT_ + gr];
    }
    #pragma unroll
    for (int ks = 0; ks < 16; ++ks){
      const int kg = ks*32 + kb;
      const f32x4 wa0 = *(const f32x4*)(W1 + kg);          const f32x4 wa1 = *(const f32x4*)(W1 + kg + 4);
      const f32x4 wb0 = *(const f32x4*)(W1 + MH_ + kg);    const f32x4 wb1 = *(const f32x4*)(W1 + MH_ + kg + 4);
      const f32x4 wc0 = *(const f32x4*)(W1 + 2*MH_ + kg);  const f32x4 wc1 = *(const f32x4*)(W1 + 2*MH_ + kg + 4);
      const f32x4 bv0 = *(const f32x4*)(b1 + kg);          const f32x4 bv1 = *(const f32x4*)(b1 + kg + 4);
      #pragma unroll
      for (int mt = 0; mt < 2; ++mt){
        union { unsigned short us[8]; bf16x8 v; } au;
        #pragma unroll
        for (int i = 0; i < 4; ++i){
          float v0 = fmaf(d[mt][2], wc0[i], fmaf(d[mt][1], wb0[i], fmaf(d[mt][0], wa0[i], bv0[i])));
          float v1 = fmaf(d[mt][2], wc1[i], fmaf(d[mt][1], wb1[i], fmaf(d[mt][0], wa1[i], bv1[i])));
          au.us[i]     = f2bf(fmaxf(v0, 0.f));
          au.us[4 + i] = f2bf(fmaxf(v1, 0.f));
        }
        afr[mt][ks] = au.v;
      }
    }
  }

  // prologue: stage regs for pass 0 (pass = 32 cols = 2048 uint4; 8/thread)
  const uint4* __restrict__ gsrc = (const uint4*)g_w2t;
  uint4 rg0, rg1, rg2, rg3, rg4, rg5, rg6, rg7;
  {
    const uint4* s = gsrc + tid;
    rg0 = s[0*256]; rg1 = s[1*256]; rg2 = s[2*256]; rg3 = s[3*256];
    rg4 = s[4*256]; rg5 = s[5*256]; rg6 = s[6*256]; rg7 = s[7*256];
  }

  float rs[2][4] = {{0.f,0.f,0.f,0.f},{0.f,0.f,0.f,0.f}};

  #pragma unroll 1
  for (int p = 0; p < 16; ++p){
    {
      uint4* bw = (uint4*)buf[p & 1] + tid;
      bw[0*256] = rg0; bw[1*256] = rg1; bw[2*256] = rg2; bw[3*256] = rg3;
      bw[4*256] = rg4; bw[5*256] = rg5; bw[6*256] = rg6; bw[7*256] = rg7;
    }
    __syncthreads();               // write visible; dbuf makes this the ONLY barrier
    if (p < 15){
      const uint4* s = gsrc + (p + 1) * 2048 + tid;
      rg0 = s[0*256]; rg1 = s[1*256]; rg2 = s[2*256]; rg3 = s[3*256];
      rg4 = s[4*256]; rg5 = s[5*256]; rg6 = s[6*256]; rg7 = s[7*256];
    }
    float b2v[2], w3v[2];
    #pragma unroll
    for (int nt = 0; nt < 2; ++nt){
      const int n = p*32 + nt*16 + c16;
      b2v[nt] = b2[n];
      w3v[nt] = W3[n];
    }

    const unsigned short* __restrict__ bb = buf[p & 1];
    f32x4 acc[2][2];
    #pragma unroll
    for (int nt = 0; nt < 2; ++nt){
      f32x4 z = {0.f,0.f,0.f,0.f};
      acc[0][nt] = z; acc[1][nt] = z;
    }
    #pragma unroll
    for (int ks = 0; ks < 16; ++ks){
      #pragma unroll
      for (int nt = 0; nt < 2; ++nt){
        const int nl = nt*16 + c16;                    // local col 0..31
        const bf16x8 bfr =
          *(const bf16x8*)&bb[(nl << 9) | ((ks*32 + kb) ^ ((nl & 7) << 3))];
        acc[0][nt] = __builtin_amdgcn_mfma_f32_16x16x32_bf16(afr[0][ks], bfr, acc[0][nt], 0, 0, 0);
        acc[1][nt] = __builtin_amdgcn_mfma_f32_16x16x32_bf16(afr[1][ks], bfr, acc[1][nt], 0, 0, 0);
      }
    }
    #pragma unroll
    for (int nt = 0; nt < 2; ++nt){
      #pragma unroll
      for (int mt = 0; mt < 2; ++mt)
        #pragma unroll
        for (int r = 0; r < 4; ++r)
          rs[mt][r] += fmaxf(acc[mt][nt][r] + b2v[nt], 0.f) * w3v[nt];
    }
  }

  // reduce across the 16 lanes (c16 bits) sharing the same C-rows
  #pragma unroll
  for (int mt = 0; mt < 2; ++mt){
    #pragma unroll
    for (int r = 0; r < 4; ++r){
      rs[mt][r] += __shfl_xor(rs[mt][r], 1);
      rs[mt][r] += __shfl_xor(rs[mt][r], 2);
      rs[mt][r] += __shfl_xor(rs[mt][r], 4);
      rs[mt][r] += __shfl_xor(rs[mt][r], 8);
    }
  }
  if (c16 == 0){
    const float bv = b3[0];
    #pragma unroll
    for (int mt = 0; mt < 2; ++mt){
      const int row = m0 + mt*16 + (l >> 4) * 4;
      #pragma unroll
      for (int r = 0; r < 4; ++r)
        out[3*BT_ + row + r] = rs[mt][r] + bv;
    }
  }
}

extern "C" void kernel_launch(void* const* d_in, const int* in_sizes, int n_in,
                              void* d_out, int out_size, void* d_ws, size_t ws_size,
                              hipStream_t stream){
  LstmArgs A;
  for (int i = 0; i < 3; ++i){
    A.x[i]    = (const float*)d_in[i];
    A.Wih[i]  = (const float*)d_in[3 + i*5 + 0];
    A.Whh[i]  = (const float*)d_in[3 + i*5 + 1];
    A.bias[i] = (const float*)d_in[3 + i*5 + 2];
    A.hw[i]   = (const float*)d_in[3 + i*5 + 3];
    A.hb[i]   = (const float*)d_in[3 + i*5 + 4];
  }
  A.out = (float*)d_out;

  prep_w2t<<<dim3(1024), dim3(256), 0, stream>>>((const float*)d_in[20]);
  prep_lstm<<<dim3(2048), dim3(256), 0, stream>>>(A);
  lstm_mfma_kernel<<<dim3(192), dim3(512), 0, stream>>>(A);
  mlp_kernel<<<dim3(1024), dim3(256), 0, stream>>>((const float*)d_out,
      (const float*)d_in[18], (const float*)d_in[19],
      (const float*)d_in[21], (const float*)d_in[22], (const float*)d_in[23],
      (float*)d_out);
}

// Round 12
// 281.554 us; speedup vs baseline: 1.3678x; 1.3678x over previous
//
#include <hip/hip_runtime.h>

#define B_ 512
#define T_ 256
#define F_ 8
#define H_ 128
#define BT_ (B_*T_)
#define MH_ 512
#define L2E 1.4426950408889634f

typedef __attribute__((ext_vector_type(4))) float f32x4;
typedef __attribute__((ext_vector_type(8))) __bf16 bf16x8;

// Static device scratch
// g_w2t: W2^T bf16, row n holds k-elems PRE-SWIZZLED: elem (k ^ ((n&7)<<3)).
__device__ unsigned short g_w2t[MH_*MH_];
// packed Whh/Wih bf16, [head][pc][k], PRE-SCALED: i,f,o rows by -log2e, g rows by +2log2e
__device__ unsigned short g_whh[3][512][128];
__device__ unsigned short g_wih[3][512][32];
__device__ unsigned short g_xbf[3][B_*T_*F_];        // x in bf16, same (B,T,F) layout

__device__ __forceinline__ unsigned short f2bf(float f){
  unsigned int u = __float_as_uint(f);
  unsigned int r = (u + 0x7FFFu + ((u >> 16) & 1u)) >> 16;  // RNE
  return (unsigned short)r;
}

#if __has_builtin(__builtin_amdgcn_exp2f)
#define EXP2F __builtin_amdgcn_exp2f
#else
#define EXP2F exp2f
#endif
#define RCPF __builtin_amdgcn_rcpf

// DPP-based partial-sum step: v += v[from partner lane], on the VALU pipe
// (vs __shfl_xor's ds_swizzle on the contended DS pipe).
// 0xB1=quad_perm(1,0,3,2)  ~xor1 ; 0x4E=quad_perm(2,3,0,1) ~xor2 ;
// 0x141=row_half_mirror (pairs complementary quads within 8) ;
// 0x140=row_mirror (pairs complementary octets within 16).
template<int CTRL>
__device__ __forceinline__ float dpp_sum_step(float v){
  int t = __builtin_amdgcn_update_dpp(0, __float_as_int(v), CTRL, 0xF, 0xF, true);
  return v + __int_as_float(t);
}

struct LstmArgs {
  const float* x[3];
  const float* Wih[3];
  const float* Whh[3];
  const float* bias[3];
  const float* hw[3];
  const float* hb[3];
  float* out;
};

// One fused prep: W2^T pack (pre-swizzled) + Whh/Wih MFMA-order pack
// (pre-scaled by +-log2e) + x to bf16.
__global__ __launch_bounds__(256) void prep_all(LstmArgs A, const float* __restrict__ W2){
  const int NW2 = MH_*MH_;       // 262144
  const int NW  = 3*512*128;     // 196608
  const int NI  = 3*512*32;      // 49152
  const int NX  = 3*B_*T_*F_;    // 3145728
  const int TOT = NW2 + NW + NI + NX;
  for (int i = blockIdx.x*256 + threadIdx.x; i < TOT; i += gridDim.x*256){
    if (i < NW2){
      int n = i >> 9;
      int k = i & 511;
      g_w2t[(n << 9) | (k ^ ((n & 7) << 3))] = f2bf(W2[(size_t)k * MH_ + n]);
    } else if (i < NW2 + NW){
      int j = i - NW2;
      int head = j >> 16;
      int r = j & 65535;
      int pc = r >> 7, k = r & 127;
      int w = pc >> 6, g = (pc >> 4) & 3, s = pc & 15;
      int row = g*128 + w*16 + s;
      float sc = (g == 2) ? (2.0f*L2E) : (-L2E);
      g_whh[head][pc][k] = f2bf(A.Whh[head][row*H_ + k] * sc);
    } else if (i < NW2 + NW + NI){
      int j = i - NW2 - NW;
      int head = j >> 14;
      int r = j & 16383;
      int pc = r >> 5, k = r & 31;
      int w = pc >> 6, g = (pc >> 4) & 3, s = pc & 15;
      int row = g*128 + w*16 + s;
      float sc = (g == 2) ? (2.0f*L2E) : (-L2E);
      g_wih[head][pc][k] = (k < 8) ? f2bf(A.Wih[head][row*F_ + k] * sc) : (unsigned short)0;
    } else {
      int j = i - NW2 - NW - NI;
      int head = j >> 20;
      int r = j & 1048575;
      g_xbf[head][r] = f2bf(A.x[head][r]);
    }
  }
}

// MFMA LSTM (round-10 configuration; shuffles moved to DPP/VALU):
//  8-batch row-spread tiles, 192 blocks. batch b -> A/C row (b>>1)*4+(b&1)
//  => 2 cells/lane. exp2-form gates, weights pre-scaled by log2e.
//  Head-dot p shfl-reduced one step LATE via DPP (VALU pipe, overlaps MFMA),
//  finalized after the barrier. One barrier per step; h double-buffered.
__global__ __launch_bounds__(512) void lstm_mfma_kernel(LstmArgs A){
  const int head   = blockIdx.x >> 6;          // 64 tiles per head, 192 blocks
  const int batch0 = (blockIdx.x & 63) * 8;
  const int tid = threadIdx.x;
  const int w   = tid >> 6;
  const int l   = tid & 63;
  const int c16 = l & 15;
  const int kb  = (l >> 4) * 8;

  const float* __restrict__ bs  = A.bias[head];
  const float* __restrict__ hwp = A.hw[head];
  const float hbv = A.hb[head][0];
  float* __restrict__ D = A.out + (size_t)head * BT_;

  // register-resident B-fragments
  bf16x8 bh[4][4];
  bf16x8 bx[4];
  #pragma unroll
  for (int g = 0; g < 4; ++g){
    const int pc = w*64 + g*16 + c16;
    #pragma unroll
    for (int kk = 0; kk < 4; ++kk)
      bh[g][kk] = *(const bf16x8*)&g_whh[head][pc][kk*32 + kb];
    bx[g] = *(const bf16x8*)&g_wih[head][pc][kb];
  }

  const int u = w*16 + c16;
  const float bi_ = bs[u]        * (-L2E);
  const float bf_ = bs[H_+u]     * (-L2E);
  const float bg_ = bs[2*H_+u]   * (2.0f*L2E);
  const float bo_ = bs[3*H_+u]   * (-L2E);
  const float hw_u = hwp[u];

  __shared__ __align__(16) unsigned short h_bf[2][16][132];
  __shared__ float part[2][8][8];

  for (int i = tid; i < 2*16*132; i += 512) ((unsigned short*)h_bf)[i] = 0;

  float cst[2] = {0.f, 0.f};
  float pp[2]  = {0.f, 0.f};

  // x A-row mapping: lane c16 supplies A-row c16; valid rows {0,1,4,5,8,9,12,13}
  const int bt = ((c16 >> 2) << 1) | (c16 & 1);          // batch-in-tile for row c16
  const bool xvalid = (l < 16) && !(l & 2);
  const unsigned short* __restrict__ xrow =
      &g_xbf[head][(size_t)(batch0 + bt) * (T_*F_)];

  bf16x8 ax_cur = {};
  if (xvalid) ax_cur = *(const bf16x8*)(xrow);

  __syncthreads();

  int cur = 0;
  for (int ts = 0; ts < T_; ++ts){
    // A-frags for current h
    bf16x8 ah[4];
    #pragma unroll
    for (int kk = 0; kk < 4; ++kk)
      ah[kk] = *(const bf16x8*)&h_bf[cur][c16][kk*32 + kb];

    // prefetch next step's x (off the critical path)
    bf16x8 ax_nxt = {};
    {
      const int tn = (ts + 1 < T_) ? ts + 1 : ts;
      if (xvalid) ax_nxt = *(const bf16x8*)(xrow + tn*F_);
    }

    // h-MFMAs first (zero init), x-MFMA last
    f32x4 acc[4];
    const f32x4 z4 = {0.f, 0.f, 0.f, 0.f};
    #pragma unroll
    for (int g = 0; g < 4; ++g)
      acc[g] = __builtin_amdgcn_mfma_f32_16x16x32_bf16(ah[0], bh[g][0], z4, 0, 0, 0);
    #pragma unroll
    for (int kk = 1; kk < 4; ++kk){
      #pragma unroll
      for (int g = 0; g < 4; ++g)
        acc[g] = __builtin_amdgcn_mfma_f32_16x16x32_bf16(ah[kk], bh[g][kk], acc[g], 0, 0, 0);
    }
    #pragma unroll
    for (int g = 0; g < 4; ++g)
      acc[g] = __builtin_amdgcn_mfma_f32_16x16x32_bf16(ax_cur, bx[g], acc[g], 0, 0, 0);

    // previous step's head-dot reduction (DPP on VALU; overlaps MFMA execution)
    if (ts > 0){
      #pragma unroll
      for (int r = 0; r < 2; ++r){
        float v = pp[r];
        v = dpp_sum_step<0xB1>(v);    // ~xor1
        v = dpp_sum_step<0x4E>(v);    // ~xor2
        v = dpp_sum_step<0x141>(v);   // half-mirror (complementary quads)
        v = dpp_sum_step<0x140>(v);   // mirror (complementary octets)
        if (c16 == 0) part[(ts-1) & 1][(l >> 4)*2 + r][w] = v;
      }
    }

    // cell update: 2 cells/lane (regs r=0,1), exp2-form gates
    #pragma unroll
    for (int r = 0; r < 2; ++r){
      const float Zi = acc[0][r] + bi_;
      const float Zf = acc[1][r] + bf_;
      const float Zg = acc[2][r] + bg_;
      const float Zo = acc[3][r] + bo_;
      const float si = RCPF(1.f + EXP2F(Zi));
      const float sf = RCPF(1.f + EXP2F(Zf));
      const float tg = 1.f - 2.f * RCPF(EXP2F(Zg) + 1.f);
      const float so = RCPF(1.f + EXP2F(Zo));
      cst[r] = sf * cst[r] + si * tg;
      const float tc = 1.f - 2.f * RCPF(EXP2F(cst[r] * (2.0f*L2E)) + 1.f);
      const float hnr = so * tc;
      h_bf[cur ^ 1][(l >> 4)*4 + r][u] = f2bf(hnr);
      pp[r] = hnr * hw_u;                       // consumed next iteration
    }

    __syncthreads();                            // new h + part visible

    // finalize D for step ts-1 (wave 0 only; overlaps other waves' next step)
    if (ts > 0 && tid < 64){
      const int b  = tid >> 3;
      const int wv = tid & 7;
      float v = part[(ts-1) & 1][b][wv];
      v = dpp_sum_step<0xB1>(v);
      v = dpp_sum_step<0x4E>(v);
      v = dpp_sum_step<0x141>(v);
      if (wv == 0) D[(size_t)(batch0 + b) * T_ + (ts-1)] = v + hbv;
    }

    ax_cur = ax_nxt;
    cur ^= 1;
  }

  // epilogue: step T-1's head-dot
  #pragma unroll
  for (int r = 0; r < 2; ++r){
    float v = pp[r];
    v = dpp_sum_step<0xB1>(v);
    v = dpp_sum_step<0x4E>(v);
    v = dpp_sum_step<0x141>(v);
    v = dpp_sum_step<0x140>(v);
    if (c16 == 0) part[(T_-1) & 1][(l >> 4)*2 + r][w] = v;
  }
  __syncthreads();
  if (tid < 64){
    const int b  = tid >> 3;
    const int wv = tid & 7;
    float v = part[(T_-1) & 1][b][wv];
    v = dpp_sum_step<0xB1>(v);
    v = dpp_sum_step<0x4E>(v);
    v = dpp_sum_step<0x141>(v);
    if (wv == 0) D[(size_t)(batch0 + b) * T_ + (T_-1)] = v + hbv;
  }
}

// Fused MLP v3 (round-10, verified ~50us): 256 threads, 128 rows/block,
// grid 1024, launch_bounds(256,2). afr computed once (128 VGPR, fits in 256
// cap). Full N in 16 passes of 32 cols; W2 slice double-buffered in LDS.
__global__ __launch_bounds__(256, 2) void mlp_kernel(
    const float* __restrict__ Dbase,
    const float* __restrict__ W1, const float* __restrict__ b1,
    const float* __restrict__ b2, const float* __restrict__ W3,
    const float* __restrict__ b3, float* __restrict__ out)
{
  __shared__ __align__(16) unsigned short buf[2][32*512];   // 2 x 32KB

  const int tid = threadIdx.x;
  const int l   = tid & 63;
  const int c16 = l & 15;
  const int kb  = (l >> 4) * 8;
  const int w   = tid >> 6;                 // 0..3
  const int m0  = blockIdx.x * 128 + w * 32;

  // A fragments for 2 M-tiles (computed once; live for whole kernel)
  bf16x8 afr[2][16];
  {
    float d[2][3];
    #pragma unroll
    for (int mt = 0; mt < 2; ++mt){
      const int gr = m0 + mt*16 + c16;
      d[mt][0] = Dbase[gr];
      d[mt][1] = Dbase[BT_ + gr];
      d[mt][2] = Dbase[2*BT_ + gr];
    }
    #pragma unroll
    for (int ks = 0; ks < 16; ++ks){
      const int kg = ks*32 + kb;
      const f32x4 wa0 = *(const f32x4*)(W1 + kg);          const f32x4 wa1 = *(const f32x4*)(W1 + kg + 4);
      const f32x4 wb0 = *(const f32x4*)(W1 + MH_ + kg);    const f32x4 wb1 = *(const f32x4*)(W1 + MH_ + kg + 4);
      const f32x4 wc0 = *(const f32x4*)(W1 + 2*MH_ + kg);  const f32x4 wc1 = *(const f32x4*)(W1 + 2*MH_ + kg + 4);
      const f32x4 bv0 = *(const f32x4*)(b1 + kg);          const f32x4 bv1 = *(const f32x4*)(b1 + kg + 4);
      #pragma unroll
      for (int mt = 0; mt < 2; ++mt){
        union { unsigned short us[8]; bf16x8 v; } au;
        #pragma unroll
        for (int i = 0; i < 4; ++i){
          float v0 = fmaf(d[mt][2], wc0[i], fmaf(d[mt][1], wb0[i], fmaf(d[mt][0], wa0[i], bv0[i])));
          float v1 = fmaf(d[mt][2], wc1[i], fmaf(d[mt][1], wb1[i], fmaf(d[mt][0], wa1[i], bv1[i])));
          au.us[i]     = f2bf(fmaxf(v0, 0.f));
          au.us[4 + i] = f2bf(fmaxf(v1, 0.f));
        }
        afr[mt][ks] = au.v;
      }
    }
  }

  // prologue: stage regs for pass 0 (pass = 32 cols = 2048 uint4; 8/thread)
  const uint4* __restrict__ gsrc = (const uint4*)g_w2t;
  uint4 rg0, rg1, rg2, rg3, rg4, rg5, rg6, rg7;
  {
    const uint4* s = gsrc + tid;
    rg0 = s[0*256]; rg1 = s[1*256]; rg2 = s[2*256]; rg3 = s[3*256];
    rg4 = s[4*256]; rg5 = s[5*256]; rg6 = s[6*256]; rg7 = s[7*256];
  }

  float rs[2][4] = {{0.f,0.f,0.f,0.f},{0.f,0.f,0.f,0.f}};

  #pragma unroll 1
  for (int p = 0; p < 16; ++p){
    {
      uint4* bw = (uint4*)buf[p & 1] + tid;
      bw[0*256] = rg0; bw[1*256] = rg1; bw[2*256] = rg2; bw[3*256] = rg3;
      bw[4*256] = rg4; bw[5*256] = rg5; bw[6*256] = rg6; bw[7*256] = rg7;
    }
    __syncthreads();               // write visible; dbuf makes this the ONLY barrier
    if (p < 15){
      const uint4* s = gsrc + (p + 1) * 2048 + tid;
      rg0 = s[0*256]; rg1 = s[1*256]; rg2 = s[2*256]; rg3 = s[3*256];
      rg4 = s[4*256]; rg5 = s[5*256]; rg6 = s[6*256]; rg7 = s[7*256];
    }
    float b2v[2], w3v[2];
    #pragma unroll
    for (int nt = 0; nt < 2; ++nt){
      const int n = p*32 + nt*16 + c16;
      b2v[nt] = b2[n];
      w3v[nt] = W3[n];
    }

    const unsigned short* __restrict__ bb = buf[p & 1];
    f32x4 acc[2][2];
    #pragma unroll
    for (int nt = 0; nt < 2; ++nt){
      f32x4 z = {0.f,0.f,0.f,0.f};
      acc[0][nt] = z; acc[1][nt] = z;
    }
    #pragma unroll
    for (int ks = 0; ks < 16; ++ks){
      #pragma unroll
      for (int nt = 0; nt < 2; ++nt){
        const int nl = nt*16 + c16;                    // local col 0..31
        const bf16x8 bfr =
          *(const bf16x8*)&bb[(nl << 9) | ((ks*32 + kb) ^ ((nl & 7) << 3))];
        acc[0][nt] = __builtin_amdgcn_mfma_f32_16x16x32_bf16(afr[0][ks], bfr, acc[0][nt], 0, 0, 0);
        acc[1][nt] = __builtin_amdgcn_mfma_f32_16x16x32_bf16(afr[1][ks], bfr, acc[1][nt], 0, 0, 0);
      }
    }
    #pragma unroll
    for (int nt = 0; nt < 2; ++nt){
      #pragma unroll
      for (int mt = 0; mt < 2; ++mt)
        #pragma unroll
        for (int r = 0; r < 4; ++r)
          rs[mt][r] += fmaxf(acc[mt][nt][r] + b2v[nt], 0.f) * w3v[nt];
    }
  }

  // reduce across the 16 lanes (c16 bits) sharing the same C-rows
  #pragma unroll
  for (int mt = 0; mt < 2; ++mt){
    #pragma unroll
    for (int r = 0; r < 4; ++r){
      rs[mt][r] += __shfl_xor(rs[mt][r], 1);
      rs[mt][r] += __shfl_xor(rs[mt][r], 2);
      rs[mt][r] += __shfl_xor(rs[mt][r], 4);
      rs[mt][r] += __shfl_xor(rs[mt][r], 8);
    }
  }
  if (c16 == 0){
    const float bv = b3[0];
    #pragma unroll
    for (int mt = 0; mt < 2; ++mt){
      const int row = m0 + mt*16 + (l >> 4) * 4;
      #pragma unroll
      for (int r = 0; r < 4; ++r)
        out[3*BT_ + row + r] = rs[mt][r] + bv;
    }
  }
}

extern "C" void kernel_launch(void* const* d_in, const int* in_sizes, int n_in,
                              void* d_out, int out_size, void* d_ws, size_t ws_size,
                              hipStream_t stream){
  LstmArgs A;
  for (int i = 0; i < 3; ++i){
    A.x[i]    = (const float*)d_in[i];
    A.Wih[i]  = (const float*)d_in[3 + i*5 + 0];
    A.Whh[i]  = (const float*)d_in[3 + i*5 + 1];
    A.bias[i] = (const float*)d_in[3 + i*5 + 2];
    A.hw[i]   = (const float*)d_in[3 + i*5 + 3];
    A.hb[i]   = (const float*)d_in[3 + i*5 + 4];
  }
  A.out = (float*)d_out;

  prep_all<<<dim3(2048), dim3(256), 0, stream>>>(A, (const float*)d_in[20]);
  lstm_mfma_kernel<<<dim3(192), dim3(512), 0, stream>>>(A);
  mlp_kernel<<<dim3(1024), dim3(256), 0, stream>>>((const float*)d_out,
      (const float*)d_in[18], (const float*)d_in[19],
      (const float*)d_in[21], (const float*)d_in[22], (const float*)d_in[23],
      (float*)d_out);
}